// Round 1
// baseline (186.453 us; speedup 1.0000x reference)
//
#include <hip/hip_runtime.h>
#include <hip/hip_bf16.h>

#define NHEAD 8
#define SEQ   2048
#define HD    64
#define EMB   512
#define NTYPE 10
#define JSPLIT 4

typedef unsigned short u16;
typedef __attribute__((ext_vector_type(8))) short short8;
typedef __attribute__((ext_vector_type(4))) float float4v;

union F8 { short8 v; uint4 u4; u16 us[8]; };

__device__ __forceinline__ float bf2f(u16 u){
  union { unsigned u; float f; } w; w.u = ((unsigned)u) << 16; return w.f;
}
__device__ __forceinline__ u16 f2bf(float f){
  union { float f; unsigned u; } w; w.f = f;
  unsigned u = w.u;
  u += 0x7fffu + ((u >> 16) & 1u);   // RNE
  return (u16)(u >> 16);
}
__device__ __forceinline__ unsigned pk2(float a, float b){
  return (unsigned)f2bf(a) | ((unsigned)f2bf(b) << 16);
}

// ---------------------------------------------------------------- pack eid -> u8
__global__ __launch_bounds__(256) void pack_eid_kernel(const int* __restrict__ eid,
                                                       unsigned* __restrict__ out){
  int i = blockIdx.x * 256 + threadIdx.x;           // one uint (4 ids) per thread
  int4 v = ((const int4*)eid)[i];
  out[i] = (unsigned)(v.x & 0xff) | ((unsigned)(v.y & 0xff) << 8) |
           ((unsigned)(v.z & 0xff) << 16) | ((unsigned)(v.w & 0xff) << 24);
}

// ---------------------------------------------------------------- QKV projection
// C[M=2048 x N=512] = A * W^T (+bias) (*scale), out bf16 head-major [h][n][d]
__global__ __launch_bounds__(256) void proj_kernel(
    const float* __restrict__ Aq, const float* __restrict__ Ak, const float* __restrict__ Av,
    const float* __restrict__ ipw, const float* __restrict__ ipb,
    u16* __restrict__ Qs, u16* __restrict__ Kb, u16* __restrict__ Vb)
{
  const int z = blockIdx.z;
  const float* A    = (z == 0) ? Aq : (z == 1 ? Ak : Av);
  const float* W    = ipw + (size_t)z * EMB * EMB;
  const float* bias = ipb + z * EMB;
  u16* O = (z == 0) ? Qs : (z == 1 ? Kb : Vb);
  const float scale = (z == 0) ? 0.125f : 1.0f;

  __shared__ u16 As[64][40];   // 80B rows: 16B aligned, 2-way bank alias (free)
  __shared__ u16 Ws[64][40];

  const int t = threadIdx.x;
  const int wave = t >> 6, lane = t & 63, lr = lane & 15, lg = lane >> 4;
  const int n0 = blockIdx.x * 64;
  const int m0 = blockIdx.y * 64;

  float4v acc[4];
#pragma unroll
  for (int c = 0; c < 4; c++) acc[c] = (float4v){0.f, 0.f, 0.f, 0.f};

  const int srow = t >> 2, skk = (t & 3) * 8;
  const float* pa = A + (size_t)(m0 + srow) * EMB + skk;
  const float* pw = W + (size_t)(n0 + srow) * EMB + skk;

  for (int k0 = 0; k0 < EMB; k0 += 32) {
    __syncthreads();
    {
      float4 a0 = *(const float4*)(pa + k0);
      float4 a1 = *(const float4*)(pa + k0 + 4);
      uint4 p; p.x = pk2(a0.x, a0.y); p.y = pk2(a0.z, a0.w);
               p.z = pk2(a1.x, a1.y); p.w = pk2(a1.z, a1.w);
      *(uint4*)&As[srow][skk] = p;
      float4 w0 = *(const float4*)(pw + k0);
      float4 w1 = *(const float4*)(pw + k0 + 4);
      uint4 q; q.x = pk2(w0.x, w0.y); q.y = pk2(w0.z, w0.w);
               q.z = pk2(w1.x, w1.y); q.w = pk2(w1.z, w1.w);
      *(uint4*)&Ws[srow][skk] = q;
    }
    __syncthreads();
    F8 af; af.u4 = *(const uint4*)&As[wave * 16 + lr][lg * 8];
#pragma unroll
    for (int c = 0; c < 4; c++) {
      F8 bf_; bf_.u4 = *(const uint4*)&Ws[c * 16 + lr][lg * 8];
      acc[c] = __builtin_amdgcn_mfma_f32_16x16x32_bf16(af.v, bf_.v, acc[c], 0, 0, 0);
    }
  }
#pragma unroll
  for (int c = 0; c < 4; c++) {
    const int e = n0 + c * 16 + lr;
    const float bb = bias[e];
#pragma unroll
    for (int r = 0; r < 4; r++) {
      const int m = m0 + wave * 16 + lg * 4 + r;
      float v = (acc[c][r] + bb) * scale;
      O[((size_t)(e >> 6) * SEQ + m) * HD + (e & 63)] = f2bf(v);
    }
  }
}

// ---------------------------------------------------------------- out projection
__global__ __launch_bounds__(256) void outproj_kernel(
    const float* __restrict__ A, const float* __restrict__ W,
    const float* __restrict__ bias, float* __restrict__ out)
{
  __shared__ u16 As[64][40];
  __shared__ u16 Ws[64][40];

  const int t = threadIdx.x;
  const int wave = t >> 6, lane = t & 63, lr = lane & 15, lg = lane >> 4;
  const int n0 = blockIdx.x * 64;
  const int m0 = blockIdx.y * 64;

  float4v acc[4];
#pragma unroll
  for (int c = 0; c < 4; c++) acc[c] = (float4v){0.f, 0.f, 0.f, 0.f};

  const int srow = t >> 2, skk = (t & 3) * 8;
  const float* pa = A + (size_t)(m0 + srow) * EMB + skk;
  const float* pw = W + (size_t)(n0 + srow) * EMB + skk;

  for (int k0 = 0; k0 < EMB; k0 += 32) {
    __syncthreads();
    {
      float4 a0 = *(const float4*)(pa + k0);
      float4 a1 = *(const float4*)(pa + k0 + 4);
      uint4 p; p.x = pk2(a0.x, a0.y); p.y = pk2(a0.z, a0.w);
               p.z = pk2(a1.x, a1.y); p.w = pk2(a1.z, a1.w);
      *(uint4*)&As[srow][skk] = p;
      float4 w0 = *(const float4*)(pw + k0);
      float4 w1 = *(const float4*)(pw + k0 + 4);
      uint4 q; q.x = pk2(w0.x, w0.y); q.y = pk2(w0.z, w0.w);
               q.z = pk2(w1.x, w1.y); q.w = pk2(w1.z, w1.w);
      *(uint4*)&Ws[srow][skk] = q;
    }
    __syncthreads();
    F8 af; af.u4 = *(const uint4*)&As[wave * 16 + lr][lg * 8];
#pragma unroll
    for (int c = 0; c < 4; c++) {
      F8 bf_; bf_.u4 = *(const uint4*)&Ws[c * 16 + lr][lg * 8];
      acc[c] = __builtin_amdgcn_mfma_f32_16x16x32_bf16(af.v, bf_.v, acc[c], 0, 0, 0);
    }
  }
#pragma unroll
  for (int c = 0; c < 4; c++) {
    const int e = n0 + c * 16 + lr;
    const float bb = bias[e];
#pragma unroll
    for (int r = 0; r < 4; r++) {
      const int m = m0 + wave * 16 + lg * 4 + r;
      out[(size_t)m * EMB + e] = acc[c][r] + bb;
    }
  }
}

// ---------------------------------------------------------------- flash attention with edge bias
// grid: x = 32 i-tiles (64 rows), y = 8 heads, z = 4 j-chunks (512 j each)
__global__ __launch_bounds__(256) void attn_kernel(
    const u16* __restrict__ Qs, const u16* __restrict__ Kb, const u16* __restrict__ Vb,
    const unsigned char* __restrict__ eidp, const float* __restrict__ EK,
    float* __restrict__ Upart, float* __restrict__ mpart, float* __restrict__ lpart)
{
  __shared__ u16 Kt[64][72];            // K tile [j][d]
  __shared__ u16 Vt[64][72];            // V tile transposed [d][j]
  __shared__ u16 Pl[4][16][72];         // per-wave P [i_local][j_local]
  __shared__ unsigned char eidt[64][64];
  __shared__ float tsl[64][12];         // type scores per row
  __shared__ float ekl[NTYPE][64];
  __shared__ float mrow[64], lrow[64], frow[64];

  const int t = threadIdx.x;
  const int wave = t >> 6, lane = t & 63, lr = lane & 15, lg = lane >> 4;
  const int i0 = blockIdx.x * 64;
  const int h  = blockIdx.y;
  const int z  = blockIdx.z;

  for (int i = t; i < NTYPE * 64; i += 256) ekl[i >> 6][i & 63] = EK[i];
  if (t < 64) { mrow[t] = -1e30f; lrow[t] = 0.f; }
  __syncthreads();

  // type scores ts[row][type] = q_scaled[row] . EK[type]
  {
    const int row = t >> 2, tt = t & 3;
    const u16* qr = Qs + ((size_t)h * SEQ + i0 + row) * HD;
    float a0 = 0.f, a1 = 0.f, a2 = 0.f;
    for (int d0 = 0; d0 < HD; d0 += 8) {
      uint4 qq = *(const uint4*)(qr + d0);
      const u16* qu = (const u16*)&qq;
#pragma unroll
      for (int e = 0; e < 8; e++) {
        float qf = bf2f(qu[e]);
        a0 += qf * ekl[tt][d0 + e];
        a1 += qf * ekl[tt + 4][d0 + e];
        a2 += qf * ekl[(tt < 2) ? (tt + 8) : 8][d0 + e];
      }
    }
    tsl[row][tt] = a0; tsl[row][tt + 4] = a1;
    if (tt < 2) tsl[row][tt + 8] = a2;
  }

  // Q fragments (A operand), held in regs all iterations
  F8 qf[2];
#pragma unroll
  for (int kc = 0; kc < 2; kc++)
    qf[kc].u4 = *(const uint4*)(Qs + ((size_t)h * SEQ + i0 + wave * 16 + lr) * HD + kc * 32 + lg * 8);

  float4v ao[4];
#pragma unroll
  for (int d = 0; d < 4; d++) ao[d] = (float4v){0.f, 0.f, 0.f, 0.f};

  const int jbase = z * (SEQ / JSPLIT);
  for (int jt = 0; jt < (SEQ / JSPLIT) / 64; jt++) {
    const int j0 = jbase + jt * 64;
    __syncthreads();
    // ---- stage K, V^T, eid tile
    {
      const int row = t >> 2, dc = (t & 3) * 16;
      const u16* kp = Kb + ((size_t)h * SEQ + j0 + row) * HD + dc;
      *(uint4*)&Kt[row][dc]     = *(const uint4*)kp;
      *(uint4*)&Kt[row][dc + 8] = *(const uint4*)(kp + 8);
      const u16* vp = Vb + ((size_t)h * SEQ + j0 + row) * HD + dc;
      uint4 v0 = *(const uint4*)vp;
      uint4 v1 = *(const uint4*)(vp + 8);
      const u16* vu = (const u16*)&v0;
#pragma unroll
      for (int e = 0; e < 8; e++) Vt[dc + e][row] = vu[e];
      vu = (const u16*)&v1;
#pragma unroll
      for (int e = 0; e < 8; e++) Vt[dc + 8 + e][row] = vu[e];
      *(uint4*)&eidt[row][dc] = *(const uint4*)(eidp + (size_t)(i0 + row) * SEQ + j0 + dc);
    }
    __syncthreads();

    // ---- S = Q K^T  (D: row=i_local=lg*4+r, col=j_local=c*16+lr)
    float4v sacc[4];
#pragma unroll
    for (int c = 0; c < 4; c++) sacc[c] = (float4v){0.f, 0.f, 0.f, 0.f};
#pragma unroll
    for (int kc = 0; kc < 2; kc++) {
#pragma unroll
      for (int c = 0; c < 4; c++) {
        F8 kf; kf.u4 = *(const uint4*)&Kt[c * 16 + lr][kc * 32 + lg * 8];
        sacc[c] = __builtin_amdgcn_mfma_f32_16x16x32_bf16(qf[kc].v, kf.v, sacc[c], 0, 0, 0);
      }
    }

    // ---- edge bias + online softmax
    float pv_[4][4];
    float rmax[4] = {-1e30f, -1e30f, -1e30f, -1e30f};
#pragma unroll
    for (int c = 0; c < 4; c++) {
#pragma unroll
      for (int r = 0; r < 4; r++) {
        const int row = wave * 16 + lg * 4 + r;
        float s = sacc[c][r] + tsl[row][eidt[row][c * 16 + lr]];
        pv_[c][r] = s;
        rmax[r] = fmaxf(rmax[r], s);
      }
    }
#pragma unroll
    for (int mm = 1; mm < 16; mm <<= 1) {
#pragma unroll
      for (int r = 0; r < 4; r++) rmax[r] = fmaxf(rmax[r], __shfl_xor(rmax[r], mm));
    }
    float mnew[4], fct[4], rsum[4] = {0.f, 0.f, 0.f, 0.f};
#pragma unroll
    for (int r = 0; r < 4; r++) {
      const int row = wave * 16 + lg * 4 + r;
      const float mo = mrow[row];
      mnew[r] = fmaxf(mo, rmax[r]);
      fct[r] = __expf(mo - mnew[r]);
    }
#pragma unroll
    for (int c = 0; c < 4; c++) {
#pragma unroll
      for (int r = 0; r < 4; r++) {
        float p = __expf(pv_[c][r] - mnew[r]);
        pv_[c][r] = p;
        rsum[r] += p;
      }
    }
#pragma unroll
    for (int mm = 1; mm < 16; mm <<= 1) {
#pragma unroll
      for (int r = 0; r < 4; r++) rsum[r] += __shfl_xor(rsum[r], mm);
    }
    if (lr == 0) {
#pragma unroll
      for (int r = 0; r < 4; r++) {
        const int row = wave * 16 + lg * 4 + r;
        mrow[row] = mnew[r];
        lrow[row] = lrow[row] * fct[r] + rsum[r];
        frow[row] = fct[r];
      }
    }
#pragma unroll
    for (int c = 0; c < 4; c++) {
#pragma unroll
      for (int r = 0; r < 4; r++)
        Pl[wave][lg * 4 + r][c * 16 + lr] = f2bf(pv_[c][r]);
    }
    // rescale O (same-wave LDS dep: DS ops in-order within wave)
    const float fo = frow[wave * 16 + lr];
#pragma unroll
    for (int d = 0; d < 4; d++) {
#pragma unroll
      for (int r = 0; r < 4; r++) ao[d][r] *= fo;
    }
    // ---- O^T += V^T P^T   (D: row=d_local, col=i_local=lr)
#pragma unroll
    for (int kc = 0; kc < 2; kc++) {
      F8 pf; pf.u4 = *(const uint4*)&Pl[wave][lr][kc * 32 + lg * 8];
#pragma unroll
      for (int db = 0; db < 4; db++) {
        F8 vf; vf.u4 = *(const uint4*)&Vt[db * 16 + lr][kc * 32 + lg * 8];
        ao[db] = __builtin_amdgcn_mfma_f32_16x16x32_bf16(vf.v, pf.v, ao[db], 0, 0, 0);
      }
    }
  }

  // ---- write partials (unnormalized U, m, l)
  {
    const size_t base = (((size_t)z * NHEAD + h) * SEQ + i0) * HD;
#pragma unroll
    for (int db = 0; db < 4; db++) {
#pragma unroll
      for (int r = 0; r < 4; r++) {
        const int d = db * 16 + lg * 4 + r;
        const int n = wave * 16 + lr;
        Upart[base + (size_t)n * HD + d] = ao[db][r];
      }
    }
    __syncthreads();
    if (t < 64) {
      mpart[((size_t)z * NHEAD + h) * SEQ + i0 + t] = mrow[t];
      lpart[((size_t)z * NHEAD + h) * SEQ + i0 + t] = lrow[t];
    }
  }
}

// ---------------------------------------------------------------- combine split-j partials
__global__ __launch_bounds__(256) void combine_kernel(
    const float* __restrict__ Upart, const float* __restrict__ mpart,
    const float* __restrict__ lpart, float* __restrict__ AO)
{
  const int rid = blockIdx.x * 4 + (threadIdx.x >> 6);   // h*SEQ + n
  const int d = threadIdx.x & 63;
  float mm[JSPLIT];
  float M = -1e30f;
#pragma unroll
  for (int zz = 0; zz < JSPLIT; zz++) {
    mm[zz] = mpart[(size_t)zz * NHEAD * SEQ + rid];
    M = fmaxf(M, mm[zz]);
  }
  float Ls = 0.f, U = 0.f;
#pragma unroll
  for (int zz = 0; zz < JSPLIT; zz++) {
    const float w = __expf(mm[zz] - M);
    Ls += w * lpart[(size_t)zz * NHEAD * SEQ + rid];
    U  += w * Upart[((size_t)zz * NHEAD * SEQ + rid) * HD + d];
  }
  const int hh = rid >> 11;
  const int n = rid & (SEQ - 1);
  AO[(size_t)n * EMB + hh * HD + d] = U / Ls;
}

// ---------------------------------------------------------------- launcher
extern "C" void kernel_launch(void* const* d_in, const int* in_sizes, int n_in,
                              void* d_out, int out_size, void* d_ws, size_t ws_size,
                              hipStream_t stream)
{
  const float* query = (const float*)d_in[0];
  const float* key_  = (const float*)d_in[1];
  const float* value = (const float*)d_in[2];
  const int*   eid   = (const int*)d_in[3];
  const float* ipw   = (const float*)d_in[4];
  const float* ipb   = (const float*)d_in[5];
  const float* opw   = (const float*)d_in[6];
  const float* opb   = (const float*)d_in[7];
  const float* ek    = (const float*)d_in[8];
  float* out = (float*)d_out;

  char* ws = (char*)d_ws;
  u16* Qs = (u16*)ws;              ws += (size_t)NHEAD * SEQ * HD * 2;
  u16* Kb = (u16*)ws;              ws += (size_t)NHEAD * SEQ * HD * 2;
  u16* Vb = (u16*)ws;              ws += (size_t)NHEAD * SEQ * HD * 2;
  unsigned char* eidp = (unsigned char*)ws; ws += (size_t)SEQ * SEQ;
  float* Upart = (float*)ws;       ws += (size_t)JSPLIT * NHEAD * SEQ * HD * 4;
  float* mpart = (float*)ws;       ws += (size_t)JSPLIT * NHEAD * SEQ * 4;
  float* lpart = (float*)ws;       ws += (size_t)JSPLIT * NHEAD * SEQ * 4;
  float* AO    = (float*)ws;       ws += (size_t)SEQ * EMB * 4;

  pack_eid_kernel<<<dim3(SEQ * SEQ / 4 / 256), dim3(256), 0, stream>>>(eid, (unsigned*)eidp);
  proj_kernel<<<dim3(EMB / 64, SEQ / 64, 3), dim3(256), 0, stream>>>(
      query, key_, value, ipw, ipb, Qs, Kb, Vb);
  attn_kernel<<<dim3(SEQ / 64, NHEAD, JSPLIT), dim3(256), 0, stream>>>(
      Qs, Kb, Vb, eidp, ek, Upart, mpart, lpart);
  combine_kernel<<<dim3(NHEAD * SEQ / 4), dim3(256), 0, stream>>>(Upart, mpart, lpart, AO);
  outproj_kernel<<<dim3(EMB / 64, SEQ / 64), dim3(256), 0, stream>>>(AO, opw, opb, out);
}

// Round 3
// 168.671 us; speedup vs baseline: 1.1054x; 1.1054x over previous
//
#include <hip/hip_runtime.h>
#include <hip/hip_bf16.h>

#define NHEAD 8
#define SEQ   2048
#define HD    64
#define EMB   512
#define NTYPE 10
#define JSPLIT 4

typedef unsigned short u16;
typedef __attribute__((ext_vector_type(8))) short short8;
typedef __attribute__((ext_vector_type(4))) float float4v;

union F8 { short8 v; uint4 u4; u16 us[8]; };

__device__ __forceinline__ float bf2f(u16 u){
  union { unsigned u; float f; } w; w.u = ((unsigned)u) << 16; return w.f;
}
__device__ __forceinline__ u16 f2bf(float f){
  union { float f; unsigned u; } w; w.f = f;
  unsigned u = w.u;
  u += 0x7fffu + ((u >> 16) & 1u);   // RNE
  return (u16)(u >> 16);
}
__device__ __forceinline__ unsigned pk2(float a, float b){
  return (unsigned)f2bf(a) | ((unsigned)f2bf(b) << 16);
}

__device__ __forceinline__ void gload_lds16(const u16* g, u16* l){
  __builtin_amdgcn_global_load_lds(
      (const __attribute__((address_space(1))) unsigned int*)g,
      (__attribute__((address_space(3))) unsigned int*)l, 16, 0, 0);
}

// ---------------------------------------------------------------- fp32 -> bf16 conversion
// q,k,v -> Abf[3][2048][512]; ipw -> Wbf[1536][512]; opw -> OWbf[512][512]
__global__ __launch_bounds__(256) void cvt_kernel(
    const float* __restrict__ q, const float* __restrict__ k, const float* __restrict__ v,
    const float* __restrict__ ipw, const float* __restrict__ opw,
    u16* __restrict__ Abf, u16* __restrict__ Wbf, u16* __restrict__ OWbf)
{
  const int gid = blockIdx.x * 256 + threadIdx.x;     // 0..524287
  const int e8 = gid * 8;
  const float* src; u16* dst; int off;
  if      (e8 < 1048576) { src = q;   dst = Abf;            off = e8; }
  else if (e8 < 2097152) { src = k;   dst = Abf + 1048576;  off = e8 - 1048576; }
  else if (e8 < 3145728) { src = v;   dst = Abf + 2097152;  off = e8 - 2097152; }
  else if (e8 < 3932160) { src = ipw; dst = Wbf;            off = e8 - 3145728; }
  else                   { src = opw; dst = OWbf;           off = e8 - 3932160; }
  float4 a = *(const float4*)(src + off);
  float4 b = *(const float4*)(src + off + 4);
  uint4 p; p.x = pk2(a.x, a.y); p.y = pk2(a.z, a.w);
           p.z = pk2(b.x, b.y); p.w = pk2(b.z, b.w);
  *(uint4*)(dst + off) = p;
}

// ---------------------------------------------------------------- pack eid -> u8
__global__ __launch_bounds__(256) void pack_eid_kernel(const int* __restrict__ eid,
                                                       unsigned* __restrict__ out){
  int i = blockIdx.x * 256 + threadIdx.x;           // one uint (4 ids) per thread
  int4 v = ((const int4*)eid)[i];
  out[i] = (unsigned)(v.x & 0xff) | ((unsigned)(v.y & 0xff) << 8) |
           ((unsigned)(v.z & 0xff) << 16) | ((unsigned)(v.w & 0xff) << 24);
}

// ---------------------------------------------------------------- 128x(BN) MFMA GEMM, C = A * B^T
// m97 structure: BK=32, global_load_lds width-16 staging, 4 waves (2x2), 4xWNF frags/wave.
// MODE 0: fused QKV (N=1536, z = n0>>9 selects A slice + output buffer; Q scaled 0.125;
//         V written TRANSPOSED [h][d][m] with packed 8B stores).
// MODE 1: out-projection, fp32 output + bias.
template<int WNF, int MODE>
__global__ __launch_bounds__(256) void gemm_bt(
    const u16* __restrict__ Aall, const u16* __restrict__ Bw,
    const float* __restrict__ bias,
    u16* __restrict__ Qs, u16* __restrict__ Kb, u16* __restrict__ Vb,
    float* __restrict__ outF)
{
  constexpr int BN = WNF * 32;
  constexpr int K  = 512;
  __shared__ u16 lds[128 * 32 + BN * 32];
  u16* As = lds;
  u16* Bs = lds + 128 * 32;

  const int t = threadIdx.x, w = t >> 6, lane = t & 63, lr = lane & 15, lg = lane >> 4;
  const int n0 = blockIdx.x * BN;
  const int m0 = blockIdx.y * 128;
  const int wm = w >> 1, wn = w & 1;

  int z = 0;
  const u16* A = Aall;
  if (MODE == 0) { z = n0 >> 9; A = Aall + (size_t)z * (2048 * 512); }

  float4v acc[4][WNF];
#pragma unroll
  for (int mi = 0; mi < 4; mi++)
#pragma unroll
    for (int ni = 0; ni < WNF; ni++) acc[mi][ni] = (float4v){0.f, 0.f, 0.f, 0.f};

  const int rb = lane >> 2, kb = (lane & 3) * 8;

  for (int k0 = 0; k0 < K; k0 += 32) {
    __syncthreads();
#pragma unroll
    for (int c = 0; c < 2; c++) {              // A: 128 rows = 8 wave-calls
      const int ci = w * 2 + c;
      gload_lds16(A + (size_t)(m0 + ci * 16 + rb) * K + k0 + kb, As + ci * 512);
    }
#pragma unroll
    for (int c = 0; c < WNF / 2; c++) {        // B: BN rows
      const int ci = w * (WNF / 2) + c;
      gload_lds16(Bw + (size_t)(n0 + ci * 16 + rb) * K + k0 + kb, Bs + ci * 512);
    }
    __syncthreads();

    F8 af[4], bfr[WNF];
#pragma unroll
    for (int mi = 0; mi < 4; mi++)
      af[mi].u4 = *(const uint4*)(As + (wm * 64 + mi * 16 + lr) * 32 + lg * 8);
#pragma unroll
    for (int ni = 0; ni < WNF; ni++)
      bfr[ni].u4 = *(const uint4*)(Bs + (wn * (BN / 2) + ni * 16 + lr) * 32 + lg * 8);
#pragma unroll
    for (int mi = 0; mi < 4; mi++)
#pragma unroll
      for (int ni = 0; ni < WNF; ni++)
        acc[mi][ni] = __builtin_amdgcn_mfma_f32_16x16x32_bf16(af[mi].v, bfr[ni].v, acc[mi][ni], 0, 0, 0);
  }

  if (MODE == 0) {
    u16* O = (z == 0) ? Qs : ((z == 1) ? Kb : Vb);
    const float scale = (z == 0) ? 0.125f : 1.0f;
#pragma unroll
    for (int mi = 0; mi < 4; mi++) {
#pragma unroll
      for (int ni = 0; ni < WNF; ni++) {
        const int n = n0 + wn * (BN / 2) + ni * 16 + lr;
        const int e = n & 511, h = e >> 6, d = e & 63;
        const float bb = bias[n];
        const int mb = m0 + wm * 64 + mi * 16 + lg * 4;
        if (z < 2) {
#pragma unroll
          for (int r = 0; r < 4; r++)
            O[((size_t)h * SEQ + mb + r) * HD + d] = f2bf((acc[mi][ni][r] + bb) * scale);
        } else {
          ushort4 pk;
          pk.x = f2bf(acc[mi][ni][0] + bb); pk.y = f2bf(acc[mi][ni][1] + bb);
          pk.z = f2bf(acc[mi][ni][2] + bb); pk.w = f2bf(acc[mi][ni][3] + bb);
          *(ushort4*)(O + ((size_t)(h * HD + d)) * SEQ + mb) = pk;   // V^T layout [h][d][m]
        }
      }
    }
  } else {
#pragma unroll
    for (int mi = 0; mi < 4; mi++) {
#pragma unroll
      for (int ni = 0; ni < WNF; ni++) {
        const int n = n0 + wn * (BN / 2) + ni * 16 + lr;
        const float bb = bias[n];
        const int mb = m0 + wm * 64 + mi * 16 + lg * 4;
#pragma unroll
        for (int r = 0; r < 4; r++)
          outF[(size_t)(mb + r) * EMB + n] = acc[mi][ni][r] + bb;
      }
    }
  }
}

// ---------------------------------------------------------------- flash attention with edge bias
// grid: x = 32 i-tiles (64 rows), y = 8 heads, z = 4 j-chunks (512 j each)
// Vb is TRANSPOSED: [h][d][j]
__global__ __launch_bounds__(256) void attn_kernel(
    const u16* __restrict__ Qs, const u16* __restrict__ Kb, const u16* __restrict__ Vb,
    const unsigned char* __restrict__ eidp, const float* __restrict__ EK,
    float* __restrict__ Upart, float* __restrict__ mpart, float* __restrict__ lpart)
{
  __shared__ u16 Kt[64][72];            // K tile [j][d]
  __shared__ u16 Vt[64][72];            // V tile transposed [d][j]
  __shared__ u16 Pl[4][16][72];         // per-wave P [i_local][j_local]
  __shared__ unsigned char eidt[64][64];
  __shared__ float tsl[64][12];         // type scores per row
  __shared__ float ekl[NTYPE][64];
  __shared__ float mrow[64], lrow[64], frow[64];

  const int t = threadIdx.x;
  const int wave = t >> 6, lane = t & 63, lr = lane & 15, lg = lane >> 4;
  const int i0 = blockIdx.x * 64;
  const int h  = blockIdx.y;
  const int z  = blockIdx.z;

  for (int i = t; i < NTYPE * 64; i += 256) ekl[i >> 6][i & 63] = EK[i];
  if (t < 64) { mrow[t] = -1e30f; lrow[t] = 0.f; }
  __syncthreads();

  // type scores ts[row][type] = q_scaled[row] . EK[type]
  {
    const int row = t >> 2, tt = t & 3;
    const u16* qr = Qs + ((size_t)h * SEQ + i0 + row) * HD;
    float a0 = 0.f, a1 = 0.f, a2 = 0.f;
    for (int d0 = 0; d0 < HD; d0 += 8) {
      uint4 qq = *(const uint4*)(qr + d0);
      const u16* qu = (const u16*)&qq;
#pragma unroll
      for (int e = 0; e < 8; e++) {
        float qf = bf2f(qu[e]);
        a0 += qf * ekl[tt][d0 + e];
        a1 += qf * ekl[tt + 4][d0 + e];
        a2 += qf * ekl[(tt < 2) ? (tt + 8) : 8][d0 + e];
      }
    }
    tsl[row][tt] = a0; tsl[row][tt + 4] = a1;
    if (tt < 2) tsl[row][tt + 8] = a2;
  }

  // Q fragments (A operand), held in regs all iterations
  F8 qf[2];
#pragma unroll
  for (int kc = 0; kc < 2; kc++)
    qf[kc].u4 = *(const uint4*)(Qs + ((size_t)h * SEQ + i0 + wave * 16 + lr) * HD + kc * 32 + lg * 8);

  float4v ao[4];
#pragma unroll
  for (int d = 0; d < 4; d++) ao[d] = (float4v){0.f, 0.f, 0.f, 0.f};

  const int jbase = z * (SEQ / JSPLIT);
  for (int jt = 0; jt < (SEQ / JSPLIT) / 64; jt++) {
    const int j0 = jbase + jt * 64;
    __syncthreads();
    // ---- stage K, V^T (vector loads from transposed global V), eid tile
    {
      const int row = t >> 2, dc = (t & 3) * 16;
      const u16* kp = Kb + ((size_t)h * SEQ + j0 + row) * HD + dc;
      *(uint4*)&Kt[row][dc]     = *(const uint4*)kp;
      *(uint4*)&Kt[row][dc + 8] = *(const uint4*)(kp + 8);
      const u16* vp = Vb + ((size_t)(h * HD + row)) * SEQ + j0 + dc;   // row is d here
      *(uint4*)&Vt[row][dc]     = *(const uint4*)vp;
      *(uint4*)&Vt[row][dc + 8] = *(const uint4*)(vp + 8);
      *(uint4*)&eidt[row][dc] = *(const uint4*)(eidp + (size_t)(i0 + row) * SEQ + j0 + dc);
    }
    __syncthreads();

    // ---- S = Q K^T  (D: row=i_local=lg*4+r, col=j_local=c*16+lr)
    float4v sacc[4];
#pragma unroll
    for (int c = 0; c < 4; c++) sacc[c] = (float4v){0.f, 0.f, 0.f, 0.f};
#pragma unroll
    for (int kc = 0; kc < 2; kc++) {
#pragma unroll
      for (int c = 0; c < 4; c++) {
        F8 kf; kf.u4 = *(const uint4*)&Kt[c * 16 + lr][kc * 32 + lg * 8];
        sacc[c] = __builtin_amdgcn_mfma_f32_16x16x32_bf16(qf[kc].v, kf.v, sacc[c], 0, 0, 0);
      }
    }

    // ---- edge bias + online softmax
    float pv_[4][4];
    float rmax[4] = {-1e30f, -1e30f, -1e30f, -1e30f};
#pragma unroll
    for (int c = 0; c < 4; c++) {
#pragma unroll
      for (int r = 0; r < 4; r++) {
        const int row = wave * 16 + lg * 4 + r;
        float s = sacc[c][r] + tsl[row][eidt[row][c * 16 + lr]];
        pv_[c][r] = s;
        rmax[r] = fmaxf(rmax[r], s);
      }
    }
#pragma unroll
    for (int mm = 1; mm < 16; mm <<= 1) {
#pragma unroll
      for (int r = 0; r < 4; r++) rmax[r] = fmaxf(rmax[r], __shfl_xor(rmax[r], mm));
    }
    float mnew[4], fct[4], rsum[4] = {0.f, 0.f, 0.f, 0.f};
#pragma unroll
    for (int r = 0; r < 4; r++) {
      const int row = wave * 16 + lg * 4 + r;
      const float mo = mrow[row];
      mnew[r] = fmaxf(mo, rmax[r]);
      fct[r] = __expf(mo - mnew[r]);
    }
#pragma unroll
    for (int c = 0; c < 4; c++) {
#pragma unroll
      for (int r = 0; r < 4; r++) {
        float p = __expf(pv_[c][r] - mnew[r]);
        pv_[c][r] = p;
        rsum[r] += p;
      }
    }
#pragma unroll
    for (int mm = 1; mm < 16; mm <<= 1) {
#pragma unroll
      for (int r = 0; r < 4; r++) rsum[r] += __shfl_xor(rsum[r], mm);
    }
    if (lr == 0) {
#pragma unroll
      for (int r = 0; r < 4; r++) {
        const int row = wave * 16 + lg * 4 + r;
        mrow[row] = mnew[r];
        lrow[row] = lrow[row] * fct[r] + rsum[r];
        frow[row] = fct[r];
      }
    }
#pragma unroll
    for (int c = 0; c < 4; c++) {
#pragma unroll
      for (int r = 0; r < 4; r++)
        Pl[wave][lg * 4 + r][c * 16 + lr] = f2bf(pv_[c][r]);
    }
    // rescale O (same-wave LDS dep: DS ops in-order within wave)
    const float fo = frow[wave * 16 + lr];
#pragma unroll
    for (int d = 0; d < 4; d++) {
#pragma unroll
      for (int r = 0; r < 4; r++) ao[d][r] *= fo;
    }
    // ---- O^T += V^T P^T   (D: row=d_local, col=i_local=lr)
#pragma unroll
    for (int kc = 0; kc < 2; kc++) {
      F8 pf; pf.u4 = *(const uint4*)&Pl[wave][lr][kc * 32 + lg * 8];
#pragma unroll
      for (int db = 0; db < 4; db++) {
        F8 vf; vf.u4 = *(const uint4*)&Vt[db * 16 + lr][kc * 32 + lg * 8];
        ao[db] = __builtin_amdgcn_mfma_f32_16x16x32_bf16(vf.v, pf.v, ao[db], 0, 0, 0);
      }
    }
  }

  // ---- write partials (unnormalized U, m, l)
  {
    const size_t base = (((size_t)z * NHEAD + h) * SEQ + i0) * HD;
#pragma unroll
    for (int db = 0; db < 4; db++) {
#pragma unroll
      for (int r = 0; r < 4; r++) {
        const int d = db * 16 + lg * 4 + r;
        const int n = wave * 16 + lr;
        Upart[base + (size_t)n * HD + d] = ao[db][r];
      }
    }
    __syncthreads();
    if (t < 64) {
      mpart[((size_t)z * NHEAD + h) * SEQ + i0 + t] = mrow[t];
      lpart[((size_t)z * NHEAD + h) * SEQ + i0 + t] = lrow[t];
    }
  }
}

// ---------------------------------------------------------------- combine split-j partials -> bf16 AO
__global__ __launch_bounds__(256) void combine_kernel(
    const float* __restrict__ Upart, const float* __restrict__ mpart,
    const float* __restrict__ lpart, u16* __restrict__ AObf)
{
  const int rid = blockIdx.x * 4 + (threadIdx.x >> 6);   // h*SEQ + n
  const int d = threadIdx.x & 63;
  float mm[JSPLIT];
  float M = -1e30f;
#pragma unroll
  for (int zz = 0; zz < JSPLIT; zz++) {
    mm[zz] = mpart[(size_t)zz * NHEAD * SEQ + rid];
    M = fmaxf(M, mm[zz]);
  }
  float Ls = 0.f, U = 0.f;
#pragma unroll
  for (int zz = 0; zz < JSPLIT; zz++) {
    const float w = __expf(mm[zz] - M);
    Ls += w * lpart[(size_t)zz * NHEAD * SEQ + rid];
    U  += w * Upart[((size_t)zz * NHEAD * SEQ + rid) * HD + d];
  }
  const int hh = rid >> 11;
  const int n = rid & (SEQ - 1);
  AObf[(size_t)n * EMB + hh * HD + d] = f2bf(U / Ls);
}

// ---------------------------------------------------------------- launcher
extern "C" void kernel_launch(void* const* d_in, const int* in_sizes, int n_in,
                              void* d_out, int out_size, void* d_ws, size_t ws_size,
                              hipStream_t stream)
{
  const float* query = (const float*)d_in[0];
  const float* key_  = (const float*)d_in[1];
  const float* value = (const float*)d_in[2];
  const int*   eid   = (const int*)d_in[3];
  const float* ipw   = (const float*)d_in[4];
  const float* ipb   = (const float*)d_in[5];
  const float* opw   = (const float*)d_in[6];
  const float* opb   = (const float*)d_in[7];
  const float* ek    = (const float*)d_in[8];
  float* out = (float*)d_out;

  char* ws = (char*)d_ws;
  u16* Abf  = (u16*)ws;            ws += (size_t)3 * SEQ * EMB * 2;        // 6 MB
  u16* Wbf  = (u16*)ws;            ws += (size_t)3 * EMB * EMB * 2;        // 1.5 MB
  u16* OWbf = (u16*)ws;            ws += (size_t)EMB * EMB * 2;            // 0.5 MB
  u16* Qs = (u16*)ws;              ws += (size_t)NHEAD * SEQ * HD * 2;
  u16* Kb = (u16*)ws;              ws += (size_t)NHEAD * SEQ * HD * 2;
  u16* Vb = (u16*)ws;              ws += (size_t)NHEAD * SEQ * HD * 2;     // transposed [h][d][j]
  unsigned char* eidp = (unsigned char*)ws; ws += (size_t)SEQ * SEQ;
  float* Upart = (float*)ws;       ws += (size_t)JSPLIT * NHEAD * SEQ * HD * 4;
  float* mpart = (float*)ws;       ws += (size_t)JSPLIT * NHEAD * SEQ * 4;
  float* lpart = (float*)ws;       ws += (size_t)JSPLIT * NHEAD * SEQ * 4;
  u16* AObf    = (u16*)ws;         ws += (size_t)SEQ * EMB * 2;

  cvt_kernel<<<dim3(2048), dim3(256), 0, stream>>>(query, key_, value, ipw, opw, Abf, Wbf, OWbf);
  pack_eid_kernel<<<dim3(SEQ * SEQ / 4 / 256), dim3(256), 0, stream>>>(eid, (unsigned*)eidp);
  gemm_bt<4, 0><<<dim3(3 * EMB / 128, SEQ / 128), dim3(256), 0, stream>>>(
      Abf, Wbf, ipb, Qs, Kb, Vb, nullptr);
  attn_kernel<<<dim3(SEQ / 64, NHEAD, JSPLIT), dim3(256), 0, stream>>>(
      Qs, Kb, Vb, eidp, ek, Upart, mpart, lpart);
  combine_kernel<<<dim3(NHEAD * SEQ / 4), dim3(256), 0, stream>>>(Upart, mpart, lpart, AObf);
  gemm_bt<2, 1><<<dim3(EMB / 64, SEQ / 128), dim3(256), 0, stream>>>(
      AObf, OWbf, opb, nullptr, nullptr, nullptr, out);
}

// Round 4
// 162.318 us; speedup vs baseline: 1.1487x; 1.0391x over previous
//
#include <hip/hip_runtime.h>
#include <hip/hip_bf16.h>

#define NHEAD 8
#define SEQ   2048
#define HD    64
#define EMB   512
#define NTYPE 10
#define JSPLIT 2

typedef unsigned short u16;
typedef __attribute__((ext_vector_type(8))) short short8;
typedef __attribute__((ext_vector_type(4))) float float4v;

union F8 { short8 v; uint4 u4; u16 us[8]; };

__device__ __forceinline__ float bf2f(u16 u){
  union { unsigned u; float f; } w; w.u = ((unsigned)u) << 16; return w.f;
}
__device__ __forceinline__ u16 f2bf(float f){
  union { float f; unsigned u; } w; w.f = f;
  unsigned u = w.u;
  u += 0x7fffu + ((u >> 16) & 1u);   // RNE
  return (u16)(u >> 16);
}
__device__ __forceinline__ unsigned pk2(float a, float b){
  return (unsigned)f2bf(a) | ((unsigned)f2bf(b) << 16);
}

__device__ __forceinline__ void gload_lds16(const u16* g, u16* l){
  __builtin_amdgcn_global_load_lds(
      (const __attribute__((address_space(1))) unsigned int*)g,
      (__attribute__((address_space(3))) unsigned int*)l, 16, 0, 0);
}

// ---------------------------------------------------------------- prep: fp32->bf16 cvt + eid pack
// blocks [0,2048): q,k,v,ipw,opw -> bf16 (8 elems/thread)
// blocks [2048,6144): eid int32 -> u8 (4 ids/thread)
__global__ __launch_bounds__(256) void prep_kernel(
    const float* __restrict__ q, const float* __restrict__ k, const float* __restrict__ v,
    const float* __restrict__ ipw, const float* __restrict__ opw,
    const int* __restrict__ eid,
    u16* __restrict__ Abf, u16* __restrict__ Wbf, u16* __restrict__ OWbf,
    unsigned* __restrict__ eidp)
{
  const int gid = blockIdx.x * 256 + threadIdx.x;
  if (blockIdx.x < 2048) {
    const int e8 = gid * 8;
    const float* src; u16* dst; int off;
    if      (e8 < 1048576) { src = q;   dst = Abf;            off = e8; }
    else if (e8 < 2097152) { src = k;   dst = Abf + 1048576;  off = e8 - 1048576; }
    else if (e8 < 3145728) { src = v;   dst = Abf + 2097152;  off = e8 - 2097152; }
    else if (e8 < 3932160) { src = ipw; dst = Wbf;            off = e8 - 3145728; }
    else                   { src = opw; dst = OWbf;           off = e8 - 3932160; }
    float4 a = *(const float4*)(src + off);
    float4 b = *(const float4*)(src + off + 4);
    uint4 p; p.x = pk2(a.x, a.y); p.y = pk2(a.z, a.w);
             p.z = pk2(b.x, b.y); p.w = pk2(b.z, b.w);
    *(uint4*)(dst + off) = p;
  } else {
    const int i = gid - 524288;
    int4 vv = ((const int4*)eid)[i];
    eidp[i] = (unsigned)(vv.x & 0xff) | ((unsigned)(vv.y & 0xff) << 8) |
              ((unsigned)(vv.z & 0xff) << 16) | ((unsigned)(vv.w & 0xff) << 24);
  }
}

// ---------------------------------------------------------------- 128x(BN) MFMA GEMM, C = A * B^T
// m97 structure: BK=32, global_load_lds width-16 staging, 4 waves (2x2), 4xWNF frags/wave.
// MODE 0: fused QKV (N=1536, z = n0>>9 selects A slice + output buffer; Q scaled 0.125;
//         V written TRANSPOSED [h][d][m] with packed 8B stores).
// MODE 1: out-projection, fp32 output + bias.
template<int WNF, int MODE>
__global__ __launch_bounds__(256) void gemm_bt(
    const u16* __restrict__ Aall, const u16* __restrict__ Bw,
    const float* __restrict__ bias,
    u16* __restrict__ Qs, u16* __restrict__ Kb, u16* __restrict__ Vb,
    float* __restrict__ outF)
{
  constexpr int BN = WNF * 32;
  constexpr int K  = 512;
  __shared__ u16 lds[128 * 32 + BN * 32];
  u16* As = lds;
  u16* Bs = lds + 128 * 32;

  const int t = threadIdx.x, w = t >> 6, lane = t & 63, lr = lane & 15, lg = lane >> 4;
  const int n0 = blockIdx.x * BN;
  const int m0 = blockIdx.y * 128;
  const int wm = w >> 1, wn = w & 1;

  int z = 0;
  const u16* A = Aall;
  if (MODE == 0) { z = n0 >> 9; A = Aall + (size_t)z * (2048 * 512); }

  float4v acc[4][WNF];
#pragma unroll
  for (int mi = 0; mi < 4; mi++)
#pragma unroll
    for (int ni = 0; ni < WNF; ni++) acc[mi][ni] = (float4v){0.f, 0.f, 0.f, 0.f};

  const int rb = lane >> 2, kb = (lane & 3) * 8;

  for (int k0 = 0; k0 < K; k0 += 32) {
    __syncthreads();
#pragma unroll
    for (int c = 0; c < 2; c++) {              // A: 128 rows = 8 wave-calls
      const int ci = w * 2 + c;
      gload_lds16(A + (size_t)(m0 + ci * 16 + rb) * K + k0 + kb, As + ci * 512);
    }
#pragma unroll
    for (int c = 0; c < WNF / 2; c++) {        // B: BN rows
      const int ci = w * (WNF / 2) + c;
      gload_lds16(Bw + (size_t)(n0 + ci * 16 + rb) * K + k0 + kb, Bs + ci * 512);
    }
    __syncthreads();

    F8 af[4], bfr[WNF];
#pragma unroll
    for (int mi = 0; mi < 4; mi++)
      af[mi].u4 = *(const uint4*)(As + (wm * 64 + mi * 16 + lr) * 32 + lg * 8);
#pragma unroll
    for (int ni = 0; ni < WNF; ni++)
      bfr[ni].u4 = *(const uint4*)(Bs + (wn * (BN / 2) + ni * 16 + lr) * 32 + lg * 8);
#pragma unroll
    for (int mi = 0; mi < 4; mi++)
#pragma unroll
      for (int ni = 0; ni < WNF; ni++)
        acc[mi][ni] = __builtin_amdgcn_mfma_f32_16x16x32_bf16(af[mi].v, bfr[ni].v, acc[mi][ni], 0, 0, 0);
  }

  if (MODE == 0) {
    u16* O = (z == 0) ? Qs : ((z == 1) ? Kb : Vb);
    const float scale = (z == 0) ? 0.125f : 1.0f;
#pragma unroll
    for (int mi = 0; mi < 4; mi++) {
#pragma unroll
      for (int ni = 0; ni < WNF; ni++) {
        const int n = n0 + wn * (BN / 2) + ni * 16 + lr;
        const int e = n & 511, h = e >> 6, d = e & 63;
        const float bb = bias[n];
        const int mb = m0 + wm * 64 + mi * 16 + lg * 4;
        if (z < 2) {
#pragma unroll
          for (int r = 0; r < 4; r++)
            O[((size_t)h * SEQ + mb + r) * HD + d] = f2bf((acc[mi][ni][r] + bb) * scale);
        } else {
          ushort4 pk;
          pk.x = f2bf(acc[mi][ni][0] + bb); pk.y = f2bf(acc[mi][ni][1] + bb);
          pk.z = f2bf(acc[mi][ni][2] + bb); pk.w = f2bf(acc[mi][ni][3] + bb);
          *(ushort4*)(O + ((size_t)(h * HD + d)) * SEQ + mb) = pk;   // V^T layout [h][d][m]
        }
      }
    }
  } else {
#pragma unroll
    for (int mi = 0; mi < 4; mi++) {
#pragma unroll
      for (int ni = 0; ni < WNF; ni++) {
        const int n = n0 + wn * (BN / 2) + ni * 16 + lr;
        const float bb = bias[n];
        const int mb = m0 + wm * 64 + mi * 16 + lg * 4;
#pragma unroll
        for (int r = 0; r < 4; r++)
          outF[(size_t)(mb + r) * EMB + n] = acc[mi][ni][r] + bb;
      }
    }
  }
}

// ---------------------------------------------------------------- flash attention with edge bias
// grid: x = 32 i-tiles (64 rows), y = 8 heads, z = 2 j-chunks (1024 j each)
// Vb is TRANSPOSED: [h][d][j].
// T14 async-STAGE: next tile's K/V/eid prefetched to regs during compute, ds_write after barrier.
// eidt columns XOR-swizzled by lg (row bits 2-3) so the 16-dword gather is bank-conflict-free.
__global__ __launch_bounds__(256) void attn_kernel(
    const u16* __restrict__ Qs, const u16* __restrict__ Kb, const u16* __restrict__ Vb,
    const unsigned char* __restrict__ eidp, const float* __restrict__ EK,
    float* __restrict__ Upart, float* __restrict__ mpart, float* __restrict__ lpart)
{
  __shared__ u16 Kt[64][72];            // K tile [j][d]
  __shared__ u16 Vt[64][72];            // V tile transposed [d][j]
  __shared__ u16 Pl[4][16][72];         // per-wave P [i_local][j_local]
  __shared__ unsigned char eidt[64][64];// col-swizzled: col' = col ^ (((row>>2)&3)<<4)
  __shared__ float tsl[64][13];         // type scores per row (+1 pad: spreads random-type gather)
  __shared__ float ekl[NTYPE][64];
  __shared__ float mrow[64], lrow[64], frow[64];

  const int t = threadIdx.x;
  const int wave = t >> 6, lane = t & 63, lr = lane & 15, lg = lane >> 4;
  const int i0 = blockIdx.x * 64;
  const int h  = blockIdx.y;
  const int z  = blockIdx.z;

  for (int i = t; i < NTYPE * 64; i += 256) ekl[i >> 6][i & 63] = EK[i];
  if (t < 64) { mrow[t] = -1e30f; lrow[t] = 0.f; }
  __syncthreads();

  // type scores ts[row][type] = q_scaled[row] . EK[type]
  {
    const int row = t >> 2, tt = t & 3;
    const u16* qr = Qs + ((size_t)h * SEQ + i0 + row) * HD;
    float a0 = 0.f, a1 = 0.f, a2 = 0.f;
    for (int d0 = 0; d0 < HD; d0 += 8) {
      uint4 qq = *(const uint4*)(qr + d0);
      const u16* qu = (const u16*)&qq;
#pragma unroll
      for (int e = 0; e < 8; e++) {
        float qf = bf2f(qu[e]);
        a0 += qf * ekl[tt][d0 + e];
        a1 += qf * ekl[tt + 4][d0 + e];
        a2 += qf * ekl[(tt < 2) ? (tt + 8) : 8][d0 + e];
      }
    }
    tsl[row][tt] = a0; tsl[row][tt + 4] = a1;
    if (tt < 2) tsl[row][tt + 8] = a2;
  }

  // Q fragments (A operand), held in regs all iterations
  F8 qf[2];
#pragma unroll
  for (int kc = 0; kc < 2; kc++)
    qf[kc].u4 = *(const uint4*)(Qs + ((size_t)h * SEQ + i0 + wave * 16 + lr) * HD + kc * 32 + lg * 8);

  float4v ao[4];
#pragma unroll
  for (int d = 0; d < 4; d++) ao[d] = (float4v){0.f, 0.f, 0.f, 0.f};

  // staging geometry (per thread): K row srow 32B, V^T row srow 32B, eid row srow 16B
  const int srow = t >> 2, sdc = (t & 3) * 16;
  const int sec = sdc ^ (((t >> 4) & 3) << 4);          // swizzled eidt col
  const int jbase = z * (SEQ / JSPLIT);
  const int NT = (SEQ / JSPLIT) / 64;

  uint4 kp0, kp1, vp0, vp1, ep0;
  // ---- prologue: load + write tile 0
  {
    const u16* kp = Kb + ((size_t)h * SEQ + jbase + srow) * HD + sdc;
    kp0 = *(const uint4*)kp; kp1 = *(const uint4*)(kp + 8);
    const u16* vp = Vb + ((size_t)(h * HD + srow)) * SEQ + jbase + sdc;
    vp0 = *(const uint4*)vp; vp1 = *(const uint4*)(vp + 8);
    ep0 = *(const uint4*)(eidp + (size_t)(i0 + srow) * SEQ + jbase + sdc);
    *(uint4*)&Kt[srow][sdc] = kp0; *(uint4*)&Kt[srow][sdc + 8] = kp1;
    *(uint4*)&Vt[srow][sdc] = vp0; *(uint4*)&Vt[srow][sdc + 8] = vp1;
    *(uint4*)&eidt[srow][sec] = ep0;
  }

  for (int jt = 0; jt < NT; jt++) {
    __syncthreads();                               // tile jt staged (and tsl on jt==0)

    // ---- T14: issue next tile's global loads now; latency hides under compute
    if (jt + 1 < NT) {
      const int jn = jbase + (jt + 1) * 64;
      const u16* kp = Kb + ((size_t)h * SEQ + jn + srow) * HD + sdc;
      kp0 = *(const uint4*)kp; kp1 = *(const uint4*)(kp + 8);
      const u16* vp = Vb + ((size_t)(h * HD + srow)) * SEQ + jn + sdc;
      vp0 = *(const uint4*)vp; vp1 = *(const uint4*)(vp + 8);
      ep0 = *(const uint4*)(eidp + (size_t)(i0 + srow) * SEQ + jn + sdc);
    }

    // ---- S = Q K^T  (D: row=i_local=lg*4+r, col=j_local=c*16+lr)
    float4v sacc[4];
#pragma unroll
    for (int c = 0; c < 4; c++) sacc[c] = (float4v){0.f, 0.f, 0.f, 0.f};
#pragma unroll
    for (int kc = 0; kc < 2; kc++) {
#pragma unroll
      for (int c = 0; c < 4; c++) {
        F8 kf; kf.u4 = *(const uint4*)&Kt[c * 16 + lr][kc * 32 + lg * 8];
        sacc[c] = __builtin_amdgcn_mfma_f32_16x16x32_bf16(qf[kc].v, kf.v, sacc[c], 0, 0, 0);
      }
    }

    // ---- edge bias + online softmax (eidt read at swizzled col (c^lg)*16+lr)
    float pv_[4][4];
    float rmax[4] = {-1e30f, -1e30f, -1e30f, -1e30f};
#pragma unroll
    for (int c = 0; c < 4; c++) {
      const int ec = ((c ^ lg) << 4) + lr;
#pragma unroll
      for (int r = 0; r < 4; r++) {
        const int row = wave * 16 + lg * 4 + r;
        float s = sacc[c][r] + tsl[row][eidt[row][ec]];
        pv_[c][r] = s;
        rmax[r] = fmaxf(rmax[r], s);
      }
    }
#pragma unroll
    for (int mm = 1; mm < 16; mm <<= 1) {
#pragma unroll
      for (int r = 0; r < 4; r++) rmax[r] = fmaxf(rmax[r], __shfl_xor(rmax[r], mm));
    }
    float mnew[4], fct[4], rsum[4] = {0.f, 0.f, 0.f, 0.f};
#pragma unroll
    for (int r = 0; r < 4; r++) {
      const int row = wave * 16 + lg * 4 + r;
      const float mo = mrow[row];
      mnew[r] = fmaxf(mo, rmax[r]);
      fct[r] = __expf(mo - mnew[r]);
    }
#pragma unroll
    for (int c = 0; c < 4; c++) {
#pragma unroll
      for (int r = 0; r < 4; r++) {
        float p = __expf(pv_[c][r] - mnew[r]);
        pv_[c][r] = p;
        rsum[r] += p;
      }
    }
#pragma unroll
    for (int mm = 1; mm < 16; mm <<= 1) {
#pragma unroll
      for (int r = 0; r < 4; r++) rsum[r] += __shfl_xor(rsum[r], mm);
    }
    if (lr == 0) {
#pragma unroll
      for (int r = 0; r < 4; r++) {
        const int row = wave * 16 + lg * 4 + r;
        mrow[row] = mnew[r];
        lrow[row] = lrow[row] * fct[r] + rsum[r];
        frow[row] = fct[r];
      }
    }
#pragma unroll
    for (int c = 0; c < 4; c++) {
#pragma unroll
      for (int r = 0; r < 4; r++)
        Pl[wave][lg * 4 + r][c * 16 + lr] = f2bf(pv_[c][r]);
    }
    // rescale O (same-wave LDS dep: DS ops in-order within wave)
    const float fo = frow[wave * 16 + lr];
#pragma unroll
    for (int d = 0; d < 4; d++) {
#pragma unroll
      for (int r = 0; r < 4; r++) ao[d][r] *= fo;
    }
    // ---- O^T += V^T P^T   (D: row=d_local, col=i_local=lr)
#pragma unroll
    for (int kc = 0; kc < 2; kc++) {
      F8 pf; pf.u4 = *(const uint4*)&Pl[wave][lr][kc * 32 + lg * 8];
#pragma unroll
      for (int db = 0; db < 4; db++) {
        F8 vf; vf.u4 = *(const uint4*)&Vt[db * 16 + lr][kc * 32 + lg * 8];
        ao[db] = __builtin_amdgcn_mfma_f32_16x16x32_bf16(vf.v, pf.v, ao[db], 0, 0, 0);
      }
    }

    __syncthreads();                               // all waves done reading tile jt
    if (jt + 1 < NT) {                             // T14: write prefetched tile jt+1
      *(uint4*)&Kt[srow][sdc] = kp0; *(uint4*)&Kt[srow][sdc + 8] = kp1;
      *(uint4*)&Vt[srow][sdc] = vp0; *(uint4*)&Vt[srow][sdc + 8] = vp1;
      *(uint4*)&eidt[srow][sec] = ep0;
    }
  }

  // ---- write partials (unnormalized U, m, l)
  {
    const size_t base = (((size_t)z * NHEAD + h) * SEQ + i0) * HD;
#pragma unroll
    for (int db = 0; db < 4; db++) {
#pragma unroll
      for (int r = 0; r < 4; r++) {
        const int d = db * 16 + lg * 4 + r;
        const int n = wave * 16 + lr;
        Upart[base + (size_t)n * HD + d] = ao[db][r];
      }
    }
    __syncthreads();
    if (t < 64) {
      mpart[((size_t)z * NHEAD + h) * SEQ + i0 + t] = mrow[t];
      lpart[((size_t)z * NHEAD + h) * SEQ + i0 + t] = lrow[t];
    }
  }
}

// ---------------------------------------------------------------- combine split-j partials -> bf16 AO
__global__ __launch_bounds__(256) void combine_kernel(
    const float* __restrict__ Upart, const float* __restrict__ mpart,
    const float* __restrict__ lpart, u16* __restrict__ AObf)
{
  const int rid = blockIdx.x * 4 + (threadIdx.x >> 6);   // h*SEQ + n
  const int d = threadIdx.x & 63;
  float mm[JSPLIT];
  float M = -1e30f;
#pragma unroll
  for (int zz = 0; zz < JSPLIT; zz++) {
    mm[zz] = mpart[(size_t)zz * NHEAD * SEQ + rid];
    M = fmaxf(M, mm[zz]);
  }
  float Ls = 0.f, U = 0.f;
#pragma unroll
  for (int zz = 0; zz < JSPLIT; zz++) {
    const float w = __expf(mm[zz] - M);
    Ls += w * lpart[(size_t)zz * NHEAD * SEQ + rid];
    U  += w * Upart[((size_t)zz * NHEAD * SEQ + rid) * HD + d];
  }
  const int hh = rid >> 11;
  const int n = rid & (SEQ - 1);
  AObf[(size_t)n * EMB + hh * HD + d] = f2bf(U / Ls);
}

// ---------------------------------------------------------------- launcher
extern "C" void kernel_launch(void* const* d_in, const int* in_sizes, int n_in,
                              void* d_out, int out_size, void* d_ws, size_t ws_size,
                              hipStream_t stream)
{
  const float* query = (const float*)d_in[0];
  const float* key_  = (const float*)d_in[1];
  const float* value = (const float*)d_in[2];
  const int*   eid   = (const int*)d_in[3];
  const float* ipw   = (const float*)d_in[4];
  const float* ipb   = (const float*)d_in[5];
  const float* opw   = (const float*)d_in[6];
  const float* opb   = (const float*)d_in[7];
  const float* ek    = (const float*)d_in[8];
  float* out = (float*)d_out;

  char* ws = (char*)d_ws;
  u16* Abf  = (u16*)ws;            ws += (size_t)3 * SEQ * EMB * 2;        // 6 MB
  u16* Wbf  = (u16*)ws;            ws += (size_t)3 * EMB * EMB * 2;        // 1.5 MB
  u16* OWbf = (u16*)ws;            ws += (size_t)EMB * EMB * 2;            // 0.5 MB
  u16* Qs = (u16*)ws;              ws += (size_t)NHEAD * SEQ * HD * 2;
  u16* Kb = (u16*)ws;              ws += (size_t)NHEAD * SEQ * HD * 2;
  u16* Vb = (u16*)ws;              ws += (size_t)NHEAD * SEQ * HD * 2;     // transposed [h][d][j]
  unsigned char* eidp = (unsigned char*)ws; ws += (size_t)SEQ * SEQ;
  float* Upart = (float*)ws;       ws += (size_t)JSPLIT * NHEAD * SEQ * HD * 4;
  float* mpart = (float*)ws;       ws += (size_t)JSPLIT * NHEAD * SEQ * 4;
  float* lpart = (float*)ws;       ws += (size_t)JSPLIT * NHEAD * SEQ * 4;
  u16* AObf    = (u16*)ws;         ws += (size_t)SEQ * EMB * 2;

  prep_kernel<<<dim3(6144), dim3(256), 0, stream>>>(
      query, key_, value, ipw, opw, eid, Abf, Wbf, OWbf, (unsigned*)eidp);
  gemm_bt<4, 0><<<dim3(3 * EMB / 128, SEQ / 128), dim3(256), 0, stream>>>(
      Abf, Wbf, ipb, Qs, Kb, Vb, nullptr);
  attn_kernel<<<dim3(SEQ / 64, NHEAD, JSPLIT), dim3(256), 0, stream>>>(
      Qs, Kb, Vb, eidp, ek, Upart, mpart, lpart);
  combine_kernel<<<dim3(NHEAD * SEQ / 4), dim3(256), 0, stream>>>(Upart, mpart, lpart, AObf);
  gemm_bt<2, 1><<<dim3(EMB / 64, SEQ / 128), dim3(256), 0, stream>>>(
      AObf, OWbf, opb, nullptr, nullptr, nullptr, out);
}